// Round 1
// 1039.065 us; speedup vs baseline: 1.0943x; 1.0943x over previous
//
#include <hip/hip_runtime.h>
#include <stdint.h>

#define BATCH   8192
#define HALL    4096
#define TPB     256
#define PERT    16                    // HALL / TPB items per thread
#define EPS     10
#define BH      33554432u             // BATCH*HALL

// ---- JAX threefry2x32, partitionable mode, key = (0, 42) -----------------
// bits[L] = o0 ^ o1, (o0,o1) = threefry2x32(key, (0, L)); L < 2^32 here.
__device__ __forceinline__ uint32_t rotl32(uint32_t x, int r) {
    return (x << r) | (x >> (32 - r));   // v_alignbit_b32
}

__device__ __forceinline__ uint32_t threefry_bits_k42(uint32_t lo) {
    const uint32_t ks0 = 0u;
    const uint32_t ks1 = 42u;
    const uint32_t ks2 = 0x1BD11BDAu ^ 42u;
    uint32_t x0 = 0u + ks0;
    uint32_t x1 = lo + ks1;
#define TF_R(r) { x0 += x1; x1 = rotl32(x1, r); x1 ^= x0; }
    TF_R(13) TF_R(15) TF_R(26) TF_R(6)   x0 += ks1; x1 += ks2 + 1u;
    TF_R(17) TF_R(29) TF_R(16) TF_R(24)  x0 += ks2; x1 += ks0 + 2u;
    TF_R(13) TF_R(15) TF_R(26) TF_R(6)   x0 += ks0; x1 += ks1 + 3u;
    TF_R(17) TF_R(29) TF_R(16) TF_R(24)  x0 += ks1; x1 += ks2 + 4u;
    TF_R(13) TF_R(15) TF_R(26) TF_R(6)   x0 += ks2; x1 += ks0 + 5u;
#undef TF_R
    return x0 ^ x1;
}

// --------------------------------------------------------------------------
// Sampling key: argmax_h p_h / a_h  ==  argmin_h q_h,  q_h = a_h * (1/p_h).
// a in log2 units (v_log_f32, 1 ULP): all comparisons are a-ratio-invariant,
// so the ln2 scale cancels — ordering is exactly preserved vs natural log.
// f==0 -> log2(0) = -inf -> q = +inf -> never selected (same outcome as the
// reference's max(f, tiny) clamp, whose huge -log(tiny) also never wins).
__global__ __launch_bounds__(TPB)
void reinforce_kernel(const float* __restrict__ X, const float* __restrict__ W,
                      const float* __restrict__ bias, int* __restrict__ out) {
#pragma clang fp contract(off)
    __shared__ float s_ip[HALL];      // per-item 1/p = s_split/ex (own-thread use)
    __shared__ float s_rm[3][4];      // per-split max, per wave
    __shared__ float s_rs[3][4];      // per-split sum, per wave
    __shared__ float s_rv[EPS + 1][4];// tail: 10 eps q-keys (min) + best-p (max)
    __shared__ int   s_ri[EPS + 1][4];

    const int b   = blockIdx.x;
    const int tid = threadIdx.x;
    const int wv  = tid >> 6;
    const int ln  = tid & 63;
    const float* xr = X + (size_t)b * (HALL * 3);

    const float w00 = W[0], w01 = W[1], w02 = W[2], bb0 = bias[0];
    const float w10 = W[3], w11 = W[4], w12 = W[5], bb1 = bias[1];
    const float w20 = W[6], w21 = W[7], w22 = W[8], bb2 = bias[2];

    // ---- logits: thread owns h = tid + 256*j ; split: j<8 ->0, j<12 ->1, else 2
    float lg[PERT];
#pragma unroll
    for (int j = 0; j < PERT; j++) {
        int h = tid + j * TPB;
        float x0 = xr[3 * h], x1 = xr[3 * h + 1], x2 = xr[3 * h + 2];
        float wa, wb, wc, bb;
        if (j < 8)       { wa = w00; wb = w01; wc = w02; bb = bb0; }
        else if (j < 12) { wa = w10; wb = w11; wc = w12; bb = bb1; }
        else             { wa = w20; wb = w21; wc = w22; bb = bb2; }
        lg[j] = ((x0 * wa + x1 * wb) + x2 * wc) + bb;
    }

    // ---- per-split max (fused 3-value wave reduce, 1 sync)
    float pm0 = -INFINITY, pm1 = -INFINITY, pm2 = -INFINITY;
#pragma unroll
    for (int j = 0; j < PERT; j++) {
        if (j < 8)       pm0 = fmaxf(pm0, lg[j]);
        else if (j < 12) pm1 = fmaxf(pm1, lg[j]);
        else             pm2 = fmaxf(pm2, lg[j]);
    }
    for (int off = 32; off; off >>= 1) {
        pm0 = fmaxf(pm0, __shfl_down(pm0, off, 64));
        pm1 = fmaxf(pm1, __shfl_down(pm1, off, 64));
        pm2 = fmaxf(pm2, __shfl_down(pm2, off, 64));
    }
    if (ln == 0) { s_rm[0][wv] = pm0; s_rm[1][wv] = pm1; s_rm[2][wv] = pm2; }
    __syncthreads();
    const float m0 = fmaxf(fmaxf(s_rm[0][0], s_rm[0][1]), fmaxf(s_rm[0][2], s_rm[0][3]));
    const float m1 = fmaxf(fmaxf(s_rm[1][0], s_rm[1][1]), fmaxf(s_rm[1][2], s_rm[1][3]));
    const float m2 = fmaxf(fmaxf(s_rm[2][0], s_rm[2][1]), fmaxf(s_rm[2][2], s_rm[2][3]));

    // ---- per-split sum of exp(l - m) (fused 3-value wave reduce, 1 sync)
    float ex[PERT];
    float ps0 = 0.f, ps1 = 0.f, ps2 = 0.f;
#pragma unroll
    for (int j = 0; j < PERT; j++) {
        float m = (j < 8) ? m0 : (j < 12) ? m1 : m2;
        float e = expf(lg[j] - m);
        ex[j] = e;
        if (j < 8)       ps0 += e;
        else if (j < 12) ps1 += e;
        else             ps2 += e;
    }
    for (int off = 32; off; off >>= 1) {
        ps0 += __shfl_down(ps0, off, 64);
        ps1 += __shfl_down(ps1, off, 64);
        ps2 += __shfl_down(ps2, off, 64);
    }
    if (ln == 0) { s_rs[0][wv] = ps0; s_rs[1][wv] = ps1; s_rs[2][wv] = ps2; }
    __syncthreads();
    const float s0 = ((s_rs[0][0] + s_rs[0][1]) + s_rs[0][2]) + s_rs[0][3];
    const float s1 = ((s_rs[1][0] + s_rs[1][1]) + s_rs[1][2]) + s_rs[1][3];
    const float s2 = ((s_rs[2][0] + s_rs[2][1]) + s_rs[2][2]) + s_rs[2][3];

    // ---- best = argmax p (via p~ = ex * (1/s); top-2 gap >> ulp so safe)
    //      stash 1/p = s/ex in LDS (read back by same thread, no sync needed)
    const float is0 = 1.0f / s0, is1 = 1.0f / s1, is2 = 1.0f / s2;
    float bv = -INFINITY; int bi = 0;
#pragma unroll
    for (int j = 0; j < PERT; j++) {
        float sS  = (j < 8) ? s0  : (j < 12) ? s1  : s2;
        float isS = (j < 8) ? is0 : (j < 12) ? is1 : is2;
        float pt = ex[j] * isS;
        int h = tid + j * TPB;
        if (pt > bv) { bv = pt; bi = h; }   // ascending h => strict > keeps first idx
        s_ip[h] = sS / ex[j];               // exact-rounded 1/p
    }

    // ---- epsilon sampling: per e keep (qmin, idx), q = (-log2 u) * (1/p)
    float qmv[EPS]; int qix[EPS];
#pragma unroll
    for (int e = 0; e < EPS; e++) { qmv[e] = INFINITY; qix[e] = 0x7fffffff; }

    const uint32_t rowbase = (uint32_t)b * (uint32_t)HALL;
#pragma unroll 1
    for (int j = 0; j < PERT; j++) {
        int h = tid + j * TPB;
        float ipj = s_ip[h];               // ds_read of own element
        uint32_t cnt = rowbase + (uint32_t)h;
#pragma unroll
        for (int e = 0; e < EPS; e++) {
            uint32_t bits = threefry_bits_k42(cnt + (uint32_t)e * BH);
            uint32_t fb = (bits >> 9) | 0x3F800000u;
            float f = __uint_as_float(fb) - 1.0f;   // [0,1), multiple of 2^-23
            float a = -__log2f(f);                  // v_log_f32, 1 ULP; f=0 -> +inf
            float q = a * ipj;
            if (q < qmv[e]) { qmv[e] = q; qix[e] = h; }  // ascending h keeps first
        }
    }

    // ---- tail: wave-reduce 10 eps (min q, idx) + best (max p, idx); ONE sync
#pragma unroll
    for (int e = 0; e < EPS; e++) {
        float q = qmv[e];
        int   i = qix[e];
        for (int off = 32; off; off >>= 1) {
            float qv = __shfl_down(q, off, 64);
            int   ri = __shfl_down(i, off, 64);
            if (qv < q || (qv == q && ri < i)) { q = qv; i = ri; }
        }
        if (ln == 0) { s_rv[e][wv] = q; s_ri[e][wv] = i; }
    }
    {
        float r = bv; int i = bi;
        for (int off = 32; off; off >>= 1) {
            float rv = __shfl_down(r, off, 64);
            int   ri = __shfl_down(i, off, 64);
            if (rv > r || (rv == r && ri < i)) { r = rv; i = ri; }
        }
        if (ln == 0) { s_rv[EPS][wv] = r; s_ri[EPS][wv] = i; }
    }
    __syncthreads();

    if (tid == 0) {
        int samp[EPS];
#pragma unroll
        for (int e = 0; e < EPS; e++) {
            float q = s_rv[e][0]; int i = s_ri[e][0];
#pragma unroll
            for (int w = 1; w < 4; w++) {
                float qv = s_rv[e][w]; int ri = s_ri[e][w];
                if (qv < q || (qv == q && ri < i)) { q = qv; i = ri; }
            }
            samp[e] = i;
        }
        float r = s_rv[EPS][0]; int best = s_ri[EPS][0];
#pragma unroll
        for (int w = 1; w < 4; w++) {
            float rv = s_rv[EPS][w]; int ri = s_ri[EPS][w];
            if (rv > r || (rv == r && ri < best)) { r = rv; best = ri; }
        }
        bool hit = false;
#pragma unroll
        for (int k = 0; k < EPS; k++) hit = hit || (samp[k] == best);
        out[b] = hit ? best : samp[EPS - 1];
    }
}

extern "C" void kernel_launch(void* const* d_in, const int* in_sizes, int n_in,
                              void* d_out, int out_size, void* d_ws, size_t ws_size,
                              hipStream_t stream) {
    const float* X    = (const float*)d_in[0];   // (8192, 12288) f32
    const float* W    = (const float*)d_in[1];   // (3, 3) f32
    const float* bias = (const float*)d_in[2];   // (3,) f32
    int* out = (int*)d_out;                      // (8192,) int32 actions
    (void)in_sizes; (void)n_in; (void)d_ws; (void)ws_size; (void)out_size;

    reinforce_kernel<<<BATCH, TPB, 0, stream>>>(X, W, bias, out);
}

// Round 2
// 1025.643 us; speedup vs baseline: 1.1087x; 1.0131x over previous
//
#include <hip/hip_runtime.h>
#include <stdint.h>

#define BATCH   8192
#define HALL    4096
#define TPB     256
#define PERT    16                    // HALL / TPB items per thread
#define EPS     10
#define BH      33554432u             // BATCH*HALL

// ---- JAX threefry2x32, partitionable mode, key = (0, 42) -----------------
// bits[L] = o0 ^ o1, (o0,o1) = threefry2x32(key, (0, L)); L < 2^32 here.
// rotl forced to v_alignbit_b32: alignbit(x,x,32-r) = rotl(x,r), 1 VALU op.
__device__ __forceinline__ uint32_t rotl32(uint32_t x, int r) {
    return __builtin_amdgcn_alignbit(x, x, 32 - r);
}

__device__ __forceinline__ uint32_t threefry_bits_k42(uint32_t lo) {
    const uint32_t ks0 = 0u;
    const uint32_t ks1 = 42u;
    const uint32_t ks2 = 0x1BD11BDAu ^ 42u;
    uint32_t x0 = 0u + ks0;
    uint32_t x1 = lo + ks1;
#define TF_R(r) { x0 += x1; x1 = rotl32(x1, r); x1 ^= x0; }
    TF_R(13) TF_R(15) TF_R(26) TF_R(6)   x0 += ks1; x1 += ks2 + 1u;
    TF_R(17) TF_R(29) TF_R(16) TF_R(24)  x0 += ks2; x1 += ks0 + 2u;
    TF_R(13) TF_R(15) TF_R(26) TF_R(6)   x0 += ks0; x1 += ks1 + 3u;
    TF_R(17) TF_R(29) TF_R(16) TF_R(24)  x0 += ks1; x1 += ks2 + 4u;
    TF_R(13) TF_R(15) TF_R(26) TF_R(6)   x0 += ks2; x1 += ks0 + 5u;
#undef TF_R
    return x0 ^ x1;
}

// --------------------------------------------------------------------------
// Sampling key: argmax_h p_h / a_h  ==  argmin_h q_h,  q_h = a_h * (1/p_h).
// a in log2 units (v_log_f32, 1 ULP): all comparisons are a-ratio-invariant,
// so the ln2 scale cancels — ordering is exactly preserved vs natural log.
// f==0 -> log2(0) = -inf -> q = +inf -> never selected (same outcome as the
// reference's max(f, tiny) clamp, whose huge -log(tiny) also never wins).
__global__ __launch_bounds__(TPB, 2)   // loosen VGPR cap: let 10 RNG chains stay live
void reinforce_kernel(const float* __restrict__ X, const float* __restrict__ W,
                      const float* __restrict__ bias, int* __restrict__ out) {
#pragma clang fp contract(off)
    __shared__ float s_ip[HALL];      // per-item 1/p = s_split/ex (own-thread use)
    __shared__ float s_rm[3][4];      // per-split max, per wave
    __shared__ float s_rs[3][4];      // per-split sum, per wave
    __shared__ float s_rv[EPS + 1][4];// tail: 10 eps q-keys (min) + best-p (max)
    __shared__ int   s_ri[EPS + 1][4];

    const int b   = blockIdx.x;
    const int tid = threadIdx.x;
    const int wv  = tid >> 6;
    const int ln  = tid & 63;
    const float* xr = X + (size_t)b * (HALL * 3);

    const float w00 = W[0], w01 = W[1], w02 = W[2], bb0 = bias[0];
    const float w10 = W[3], w11 = W[4], w12 = W[5], bb1 = bias[1];
    const float w20 = W[6], w21 = W[7], w22 = W[8], bb2 = bias[2];

    // ---- logits: thread owns h = tid + 256*j ; split: j<8 ->0, j<12 ->1, else 2
    float lg[PERT];
#pragma unroll
    for (int j = 0; j < PERT; j++) {
        int h = tid + j * TPB;
        float x0 = xr[3 * h], x1 = xr[3 * h + 1], x2 = xr[3 * h + 2];
        float wa, wb, wc, bb;
        if (j < 8)       { wa = w00; wb = w01; wc = w02; bb = bb0; }
        else if (j < 12) { wa = w10; wb = w11; wc = w12; bb = bb1; }
        else             { wa = w20; wb = w21; wc = w22; bb = bb2; }
        lg[j] = ((x0 * wa + x1 * wb) + x2 * wc) + bb;
    }

    // ---- per-split max (fused 3-value wave reduce, 1 sync)
    float pm0 = -INFINITY, pm1 = -INFINITY, pm2 = -INFINITY;
#pragma unroll
    for (int j = 0; j < PERT; j++) {
        if (j < 8)       pm0 = fmaxf(pm0, lg[j]);
        else if (j < 12) pm1 = fmaxf(pm1, lg[j]);
        else             pm2 = fmaxf(pm2, lg[j]);
    }
    for (int off = 32; off; off >>= 1) {
        pm0 = fmaxf(pm0, __shfl_down(pm0, off, 64));
        pm1 = fmaxf(pm1, __shfl_down(pm1, off, 64));
        pm2 = fmaxf(pm2, __shfl_down(pm2, off, 64));
    }
    if (ln == 0) { s_rm[0][wv] = pm0; s_rm[1][wv] = pm1; s_rm[2][wv] = pm2; }
    __syncthreads();
    const float m0 = fmaxf(fmaxf(s_rm[0][0], s_rm[0][1]), fmaxf(s_rm[0][2], s_rm[0][3]));
    const float m1 = fmaxf(fmaxf(s_rm[1][0], s_rm[1][1]), fmaxf(s_rm[1][2], s_rm[1][3]));
    const float m2 = fmaxf(fmaxf(s_rm[2][0], s_rm[2][1]), fmaxf(s_rm[2][2], s_rm[2][3]));

    // ---- per-split sum of exp(l - m) (fused 3-value wave reduce, 1 sync)
    float ex[PERT];
    float ps0 = 0.f, ps1 = 0.f, ps2 = 0.f;
#pragma unroll
    for (int j = 0; j < PERT; j++) {
        float m = (j < 8) ? m0 : (j < 12) ? m1 : m2;
        float e = expf(lg[j] - m);
        ex[j] = e;
        if (j < 8)       ps0 += e;
        else if (j < 12) ps1 += e;
        else             ps2 += e;
    }
    for (int off = 32; off; off >>= 1) {
        ps0 += __shfl_down(ps0, off, 64);
        ps1 += __shfl_down(ps1, off, 64);
        ps2 += __shfl_down(ps2, off, 64);
    }
    if (ln == 0) { s_rs[0][wv] = ps0; s_rs[1][wv] = ps1; s_rs[2][wv] = ps2; }
    __syncthreads();
    const float s0 = ((s_rs[0][0] + s_rs[0][1]) + s_rs[0][2]) + s_rs[0][3];
    const float s1 = ((s_rs[1][0] + s_rs[1][1]) + s_rs[1][2]) + s_rs[1][3];
    const float s2 = ((s_rs[2][0] + s_rs[2][1]) + s_rs[2][2]) + s_rs[2][3];

    // ---- best = argmax p (via p~ = ex * (1/s); top-2 gap >> ulp so safe)
    //      stash 1/p = s/ex in LDS (read back by same thread, no sync needed)
    const float is0 = 1.0f / s0, is1 = 1.0f / s1, is2 = 1.0f / s2;
    float bv = -INFINITY; int bi = 0;
#pragma unroll
    for (int j = 0; j < PERT; j++) {
        float sS  = (j < 8) ? s0  : (j < 12) ? s1  : s2;
        float isS = (j < 8) ? is0 : (j < 12) ? is1 : is2;
        float pt = ex[j] * isS;
        int h = tid + j * TPB;
        if (pt > bv) { bv = pt; bi = h; }   // ascending h => strict > keeps first idx
        s_ip[h] = sS / ex[j];               // exact-rounded 1/p
    }

    // ---- epsilon sampling: per e keep (qmin, idx), q = (-log2 u) * (1/p)
    float qmv[EPS]; int qix[EPS];
#pragma unroll
    for (int e = 0; e < EPS; e++) { qmv[e] = INFINITY; qix[e] = 0x7fffffff; }

    const uint32_t rowbase = (uint32_t)b * (uint32_t)HALL;
#pragma unroll 1
    for (int j = 0; j < PERT; j++) {
        int h = tid + j * TPB;
        float ipj = s_ip[h];               // ds_read of own element
        uint32_t cnt = rowbase + (uint32_t)h;
#pragma unroll
        for (int e = 0; e < EPS; e++) {
            uint32_t bits = threefry_bits_k42(cnt + (uint32_t)e * BH);
            // fb = (bits>>9) | 0x3F800000  ==  ((0x7F:bits) >> 9)[31:0]  (1 op)
            uint32_t fb = __builtin_amdgcn_alignbit(0x7Fu, bits, 9);
            float f = __uint_as_float(fb) - 1.0f;   // [0,1), multiple of 2^-23
            float a = -__log2f(f);                  // v_log_f32, 1 ULP; f=0 -> +inf
            float q = a * ipj;
            if (q < qmv[e]) { qmv[e] = q; qix[e] = h; }  // ascending h keeps first
        }
    }

    // ---- tail: wave-reduce 10 eps (min q, idx) + best (max p, idx); ONE sync
#pragma unroll
    for (int e = 0; e < EPS; e++) {
        float q = qmv[e];
        int   i = qix[e];
        for (int off = 32; off; off >>= 1) {
            float qv = __shfl_down(q, off, 64);
            int   ri = __shfl_down(i, off, 64);
            if (qv < q || (qv == q && ri < i)) { q = qv; i = ri; }
        }
        if (ln == 0) { s_rv[e][wv] = q; s_ri[e][wv] = i; }
    }
    {
        float r = bv; int i = bi;
        for (int off = 32; off; off >>= 1) {
            float rv = __shfl_down(r, off, 64);
            int   ri = __shfl_down(i, off, 64);
            if (rv > r || (rv == r && ri < i)) { r = rv; i = ri; }
        }
        if (ln == 0) { s_rv[EPS][wv] = r; s_ri[EPS][wv] = i; }
    }
    __syncthreads();

    if (tid == 0) {
        int samp[EPS];
#pragma unroll
        for (int e = 0; e < EPS; e++) {
            float q = s_rv[e][0]; int i = s_ri[e][0];
#pragma unroll
            for (int w = 1; w < 4; w++) {
                float qv = s_rv[e][w]; int ri = s_ri[e][w];
                if (qv < q || (qv == q && ri < i)) { q = qv; i = ri; }
            }
            samp[e] = i;
        }
        float r = s_rv[EPS][0]; int best = s_ri[EPS][0];
#pragma unroll
        for (int w = 1; w < 4; w++) {
            float rv = s_rv[EPS][w]; int ri = s_ri[EPS][w];
            if (rv > r || (rv == r && ri < best)) { r = rv; best = ri; }
        }
        bool hit = false;
#pragma unroll
        for (int k = 0; k < EPS; k++) hit = hit || (samp[k] == best);
        out[b] = hit ? best : samp[EPS - 1];
    }
}

extern "C" void kernel_launch(void* const* d_in, const int* in_sizes, int n_in,
                              void* d_out, int out_size, void* d_ws, size_t ws_size,
                              hipStream_t stream) {
    const float* X    = (const float*)d_in[0];   // (8192, 12288) f32
    const float* W    = (const float*)d_in[1];   // (3, 3) f32
    const float* bias = (const float*)d_in[2];   // (3,) f32
    int* out = (int*)d_out;                      // (8192,) int32 actions
    (void)in_sizes; (void)n_in; (void)d_ws; (void)ws_size; (void)out_size;

    reinforce_kernel<<<BATCH, TPB, 0, stream>>>(X, W, bias, out);
}